// Round 16
// baseline (156.071 us; speedup 1.0000x reference)
//
#include <hip/hip_runtime.h>
#include <hip/hip_bf16.h>

#define Bsz  4096
#define Tn   256
#define CIN  16
#define NCLS 10
#define MB   16          // full 16-row MFMA tile per block
#define SH   72          // comb row stride in shorts (h-only: 64 + 8 pad; 144B = 16B-aligned)

typedef __attribute__((ext_vector_type(8))) short short8;
typedef __attribute__((ext_vector_type(4))) float f32x4;

#if __has_builtin(__builtin_amdgcn_exp2f)
#define EXP2F(x) __builtin_amdgcn_exp2f(x)
#else
#define EXP2F(x) exp2f(x)
#endif
#define RCPF(x) __builtin_amdgcn_rcpf(x)

#define LOG2E 1.442695041f
#define LN2   0.6931471806f

// LDS-only barrier: order LDS writes/reads across waves WITHOUT draining
// vmcnt (global x loads + output stores stay in flight across steps).
#define BARRIER_LDS() do {                                     \
    asm volatile("s_waitcnt lgkmcnt(0)" ::: "memory");         \
    __builtin_amdgcn_s_barrier();                              \
} while (0)

__device__ inline ushort f2bf(float f) {
    union { float f; unsigned u; } x; x.f = f;
    return (ushort)((x.u + 0x7FFF + ((x.u >> 16) & 1)) >> 16);  // RNE
}
__device__ inline unsigned cvt_pk_bf16(float lo, float hi) {
    unsigned d;
    asm("v_cvt_pk_bf16_f32 %0, %1, %2" : "=v"(d) : "v"(lo), "v"(hi));
    return d;
}
__device__ inline short8 pack_bf8(float4 a, float4 b) {
    union { unsigned u[4]; short8 s; } r;
    r.u[0] = cvt_pk_bf16(a.x, a.y); r.u[1] = cvt_pk_bf16(a.z, a.w);
    r.u[2] = cvt_pk_bf16(b.x, b.y); r.u[3] = cvt_pk_bf16(b.z, b.w);
    return r.s;
}
// exponent-only ~1/x (x > 1, normal): result y with den*y in [1,2)
__device__ inline float rcp_exp_approx(float x) {
    union { float f; unsigned u; } a; a.f = x;
    union { unsigned u; float f; } y;
    y.u = 0x7F000000u - (a.u & 0x7F800000u);
    return y.f;
}

// 8 waves, 2/SIMD. Gate waves 0-3 (uw): swapped-operand gate MFMA
// (D[m=unit][n=batch]) with C = xz (x-projection precomputed LAST step, off
// the h critical path). Activation uses SCALE-INVARIANT homogenized Pade(7,6)
// tanh on the (num,den) pair — the cn-division rcp moves OFF the critical
// path (only next step needs cn). Head waves 4-7: head logits MFMA +
// softmax/pnd/stores + x pipeline. One LDS barrier/step. comb h-only.
__global__ __launch_bounds__(512, 2) void dualrnn_fused(
    const float* __restrict__ x,  const float* __restrict__ Wl, const float* __restrict__ bl,
    const float* __restrict__ Wc, const float* __restrict__ bc,
    const float* __restrict__ Wd, const float* __restrict__ bd,
    float* __restrict__ out)
{
    __shared__ alignas(16) ushort comb[2][16][SH];   // h_t double-buffered, bf16
    const int tid  = threadIdx.x;
    const int wave = tid >> 6;
    const int lane = tid & 63;
    const int col  = lane & 15;
    const int grp  = lane >> 4;
    const int b0   = blockIdx.x * MB;
    const bool gatew = (wave < 4);
    const int uw = wave & 3;

    for (int i = tid; i < 16 * SH; i += 512) ((ushort*)comb[0])[i] = 0;

    // ---- weights ----
    short8 wh[4][2]; short8 wx[4]; f32x4 biasv[4];
    short8 wcd[2] = {}; f32x4 bcdv = {0, 0, 0, 0};
    if (gatew) {
#pragma unroll
        for (int g = 0; g < 4; ++g) {
            const float sc = (g == 3) ? 2.f * LOG2E : -LOG2E;
#pragma unroll
            for (int j = 0; j < 4; ++j)
                biasv[g][j] = bl[g * 64 + uw * 16 + grp * 4 + j] * sc;
            const int R = g * 64 + uw * 16 + col;
#pragma unroll
            for (int kt = 0; kt < 2; ++kt)
#pragma unroll
                for (int i = 0; i < 8; ++i)
                    wh[g][kt][i] = (short)f2bf(Wl[R * 80 + 16 + kt * 32 + grp * 8 + i] * sc);
#pragma unroll
            for (int i = 0; i < 8; ++i)
                wx[g][i] = (grp < 2) ? (short)f2bf(Wl[R * 80 + grp * 8 + i] * sc) : (short)0;
        }
    } else {
        // head (unswapped): class lanes fold +log2e; dec lane folds -log2e.
#pragma unroll
        for (int kt = 0; kt < 2; ++kt)
#pragma unroll
            for (int i = 0; i < 8; ++i) {
                const int k = kt * 32 + grp * 8 + i;
                float v = 0.f;
                if (col < 10)       v = Wc[col * 64 + k] * LOG2E;
                else if (col == 10) v = Wd[k] * -LOG2E;
                wcd[kt][i] = (short)f2bf(v);
            }
        const float bv = (col < 10) ? bc[col] * LOG2E
                       : ((col == 10) ? bd[0] * -LOG2E : 0.f);
        bcdv = (f32x4){bv, bv, bv, bv};
    }

    // ---- gate x pipeline: xz[g] = Wx x_t + bias, computed one step ahead ----
    const float* xrow = x + ((size_t)(b0 + col) * Tn) * CIN + grp * 8;  // valid grp<2
    float4 xfA = {0, 0, 0, 0}, xfB = {0, 0, 0, 0};    // floats of x_{t+1}
    f32x4 xz[4] = {};
    const float* xp = xrow + 2 * CIN;                 // x_{t+2} onward
    if (gatew) {
        short8 x0 = {0, 0, 0, 0, 0, 0, 0, 0};
        if (grp < 2) {
            const float4 a = *(const float4*)(xrow);
            const float4 b = *(const float4*)(xrow + 4);
            x0 = pack_bf8(a, b);
            xfA = *(const float4*)(xrow + CIN);
            xfB = *(const float4*)(xrow + CIN + 4);
        }
#pragma unroll
        for (int g = 0; g < 4; ++g)
            xz[g] = __builtin_amdgcn_mfma_f32_16x16x32_bf16(wx[g], x0, biasv[g], 0, 0, 0);
        __builtin_amdgcn_s_setprio(1);   // gate waves are the critical role
    }

    __syncthreads();   // comb[0] zero-fill visible

    float cst[4] = {0, 0, 0, 0};  // gates: c[unit=uw*16+grp*4+j][batch=col]
    float pnd = 1.f;              // head, lanes col==10, row grp*4+uw

    const int row = grp * 4 + uw;        // head-output row this head thread owns
    float* lp_p = out + ((size_t)(b0 + row) * Tn) * NCLS + col;              // [B][T][10]
    float* pt_p = out + (size_t)Bsz * Tn * NCLS + (size_t)(b0 + row) * Tn;   // [B][T]

    for (int t = 0; t < Tn; ++t) {
        const ushort (*rdb)[SH] = comb[t & 1];
        ushort (*wrb)[SH] = comb[(t + 1) & 1];
        if (gatew) {
            // critical path: reads -> 2-chained MFMA (C = xz) -> act -> write
            const short8 hb0 = *(const short8*)&rdb[col][grp * 8];
            const short8 hb1 = *(const short8*)&rdb[col][32 + grp * 8];
            f32x4 acc[4];
#pragma unroll
            for (int g = 0; g < 4; ++g) {
                f32x4 z = __builtin_amdgcn_mfma_f32_16x16x32_bf16(wh[g][0], hb0, xz[g], 0, 0, 0);
                acc[g] = __builtin_amdgcn_mfma_f32_16x16x32_bf16(wh[g][1], hb1, z, 0, 0, 0);
            }
            // off-CP: xz for t+1 from x_{t+1} regs; then issue x_{t+2} loads
            const short8 xn = pack_bf8(xfA, xfB);   // grp>=2 lanes garbage, wx=0 kills
            float4 nA = {0, 0, 0, 0}, nB = {0, 0, 0, 0};
            if (t + 2 < Tn && grp < 2) {
                nA = *(const float4*)(xp);
                nB = *(const float4*)(xp + 4);
            }
            xp += CIN;
#pragma unroll
            for (int g = 0; g < 4; ++g)
                xz[g] = __builtin_amdgcn_mfma_f32_16x16x32_bf16(wx[g], xn, biasv[g], 0, 0, 0);
            xfA = nA; xfB = nB;
            // activations: c_next = num/den computed OFF-chain (needed next
            // step only). h = tanh(num/den)*sigmoid(o) via homogenized
            // Pade(7,6) on the exponent-normalized pair (n1,d1), ONE rcp on
            // the chain.
            float h[4];
#pragma unroll
            for (int j = 0; j < 4; ++j) {
                const float ei = EXP2F(acc[0][j]);
                const float ef = EXP2F(acc[1][j]);
                const float eo = EXP2F(acc[2][j]);
                const float eg = EXP2F(acc[3][j]);
                const float A  = 1.f + ei, Bv = 1.f + ef;
                const float G1 = eg + 1.f, G2 = eg - 1.f, O = 1.f + eo;
                const float t0  = A * G1;
                const float num = __builtin_fmaf(cst[j], t0, G2 * Bv);
                const float den = Bv * t0;             // den > 1 always
                cst[j] = num * RCPF(den);              // off critical path
                const float y  = rcp_exp_approx(den);  // 2 int ops
                const float n1 = num * y;              // n1/d1 == num/den
                const float d1 = den * y;              // d1 in [1,2)
                const float w  = n1 * n1, v = d1 * d1;
                const float v2 = v * v, v3 = v2 * v;
                const float P = __builtin_fmaf(w,
                                  __builtin_fmaf(w, __builtin_fmaf(378.f, v, w),
                                                 17325.f * v2), 135135.f * v3);
                const float Q = __builtin_fmaf(w,
                                  __builtin_fmaf(w, __builtin_fmaf(3150.f, v, 28.f * w),
                                                 62370.f * v2), 135135.f * v3);
                h[j] = (n1 * P) * RCPF(d1 * Q * O);    // tanh(c) * sigmoid(o)
            }
            const unsigned d0 = cvt_pk_bf16(h[0], h[1]);
            const unsigned d1p = cvt_pk_bf16(h[2], h[3]);
            *(uint2*)&wrb[col][uw * 16 + grp * 4] = (uint2){d0, d1p};
        } else {
            // head logits on h_{t-1} (rdb), softmax/store for step t-1
            const short8 ha0 = *(const short8*)&rdb[col][grp * 8];
            const short8 ha1 = *(const short8*)&rdb[col][32 + grp * 8];
            f32x4 cz = bcdv;
            cz = __builtin_amdgcn_mfma_f32_16x16x32_bf16(ha0, wcd[0], cz, 0, 0, 0);
            cz = __builtin_amdgcn_mfma_f32_16x16x32_bf16(ha1, wcd[1], cz, 0, 0, 0);
            if (t > 0) {
                // v pre-scaled: col<10 = logit*log2e ; col==10 = -dec_logit*log2e
                float v = (uw & 1) ? ((uw & 2) ? cz[3] : cz[1])
                                   : ((uw & 2) ? cz[2] : cz[0]);
                const float e = EXP2F(v);              // one exp2 serves both paths
                float s = (col < 10) ? e : 0.f;
                s += __int_as_float(__builtin_amdgcn_ds_swizzle(__float_as_int(s), 0x041F));
                s += __int_as_float(__builtin_amdgcn_ds_swizzle(__float_as_int(s), 0x081F));
                s += __int_as_float(__builtin_amdgcn_ds_swizzle(__float_as_int(s), 0x101F));
                s += __int_as_float(__builtin_amdgcn_ds_swizzle(__float_as_int(s), 0x201F));
                const float lse = __logf(s);
                if (col < 10) {
                    lp_p[0] = v * LN2 - lse;           // natural log-softmax
                } else if (col == 10) {
                    const float d = RCPF(1.f + e);     // sigmoid(dec)
                    pt_p[0] = d * pnd;
                    pnd *= (1.f - d);
                }
                lp_p += NCLS;
                pt_p += 1;
            }
        }
        BARRIER_LDS();
    }

    // epilogue: output step Tn-1 from h_{Tn-1} in comb[Tn&1] (head waves)
    if (!gatew) {
        const ushort (*rdb)[SH] = comb[Tn & 1];
        const short8 ha0 = *(const short8*)&rdb[col][grp * 8];
        const short8 ha1 = *(const short8*)&rdb[col][32 + grp * 8];
        f32x4 cz = bcdv;
        cz = __builtin_amdgcn_mfma_f32_16x16x32_bf16(ha0, wcd[0], cz, 0, 0, 0);
        cz = __builtin_amdgcn_mfma_f32_16x16x32_bf16(ha1, wcd[1], cz, 0, 0, 0);
        float v = (uw & 1) ? ((uw & 2) ? cz[3] : cz[1])
                           : ((uw & 2) ? cz[2] : cz[0]);
        const float e = EXP2F(v);
        float s = (col < 10) ? e : 0.f;
        s += __int_as_float(__builtin_amdgcn_ds_swizzle(__float_as_int(s), 0x041F));
        s += __int_as_float(__builtin_amdgcn_ds_swizzle(__float_as_int(s), 0x081F));
        s += __int_as_float(__builtin_amdgcn_ds_swizzle(__float_as_int(s), 0x101F));
        s += __int_as_float(__builtin_amdgcn_ds_swizzle(__float_as_int(s), 0x201F));
        const float lse = __logf(s);
        if (col < 10)       lp_p[0] = v * LN2 - lse;
        else if (col == 10) pt_p[0] = pnd;   // is_last: Pt = pnd_{T-1}
    }
}

extern "C" void kernel_launch(void* const* d_in, const int* in_sizes, int n_in,
                              void* d_out, int out_size, void* d_ws, size_t ws_size,
                              hipStream_t stream) {
    const float* x  = (const float*)d_in[0];
    const float* Wl = (const float*)d_in[1];
    const float* bl = (const float*)d_in[2];
    const float* Wc = (const float*)d_in[3];
    const float* bc = (const float*)d_in[4];
    const float* Wd = (const float*)d_in[5];
    const float* bd = (const float*)d_in[6];
    float* out = (float*)d_out;

    hipLaunchKernelGGL(dualrnn_fused, dim3(Bsz / MB), dim3(512), 0, stream,
                       x, Wl, bl, Wc, bc, Wd, bd, out);
}

// Round 17
// 135.355 us; speedup vs baseline: 1.1530x; 1.1530x over previous
//
#include <hip/hip_runtime.h>
#include <hip/hip_bf16.h>

#define Bsz  4096
#define Tn   256
#define CIN  16
#define NCLS 10
#define MB   16          // full 16-row MFMA tile per block
#define SH   72          // comb row stride in shorts (h-only: 64 + 8 pad; 144B = 16B-aligned)

typedef __attribute__((ext_vector_type(8))) short short8;
typedef __attribute__((ext_vector_type(4))) float f32x4;

#if __has_builtin(__builtin_amdgcn_exp2f)
#define EXP2F(x) __builtin_amdgcn_exp2f(x)
#else
#define EXP2F(x) exp2f(x)
#endif
#define RCPF(x) __builtin_amdgcn_rcpf(x)

#define LOG2E 1.442695041f
#define LN2   0.6931471806f

// LDS-only barrier: order LDS writes/reads across waves WITHOUT draining
// vmcnt (global x loads + output stores stay in flight across steps).
#define BARRIER_LDS() do {                                     \
    asm volatile("s_waitcnt lgkmcnt(0)" ::: "memory");         \
    __builtin_amdgcn_s_barrier();                              \
} while (0)

__device__ inline ushort f2bf(float f) {
    union { float f; unsigned u; } x; x.f = f;
    return (ushort)((x.u + 0x7FFF + ((x.u >> 16) & 1)) >> 16);  // RNE
}
__device__ inline unsigned cvt_pk_bf16(float lo, float hi) {
    unsigned d;
    asm("v_cvt_pk_bf16_f32 %0, %1, %2" : "=v"(d) : "v"(lo), "v"(hi));
    return d;
}
__device__ inline short8 pack_bf8(float4 a, float4 b) {
    union { unsigned u[4]; short8 s; } r;
    r.u[0] = cvt_pk_bf16(a.x, a.y); r.u[1] = cvt_pk_bf16(a.z, a.w);
    r.u[2] = cvt_pk_bf16(b.x, b.y); r.u[3] = cvt_pk_bf16(b.z, b.w);
    return r.s;
}

// 8 waves, 2/SIMD. Gate waves 0-3 (uw): swapped-operand gate MFMA
// (D[m=unit][n=batch]) with C = xz (x-projection precomputed LAST step, off
// the h critical path), activations all j, packed b64 h-write. Head waves
// 4-7: head logits MFMA + softmax/pnd/stores + x pipeline for their own xz.
// One LDS barrier per step. comb holds h only (x bypasses LDS entirely).
//
// Converged structure (R11 of 16 rounds). Falsified alternatives: 3 waves/SIMD
// (R4), 1 wave/SIMD (R5), MB=8 (R6), vmcnt-draining barrier (R7 = null),
// acc-transfer via LDS (R8), batched rcp (R9 null), duplicated-MFMA rebalance
// (R10), source reorder (R12 null), xzT producer handoff (R13/R14), parallel
// MFMA + VALU add (R15), homogenized Pade (R16). Wall = issue/chain balance.
__global__ __launch_bounds__(512, 2) void dualrnn_fused(
    const float* __restrict__ x,  const float* __restrict__ Wl, const float* __restrict__ bl,
    const float* __restrict__ Wc, const float* __restrict__ bc,
    const float* __restrict__ Wd, const float* __restrict__ bd,
    float* __restrict__ out)
{
    __shared__ alignas(16) ushort comb[2][16][SH];   // h_t double-buffered, bf16
    const int tid  = threadIdx.x;
    const int wave = tid >> 6;
    const int lane = tid & 63;
    const int col  = lane & 15;
    const int grp  = lane >> 4;
    const int b0   = blockIdx.x * MB;
    const bool gatew = (wave < 4);
    const int uw = wave & 3;

    for (int i = tid; i < 16 * SH; i += 512) ((ushort*)comb[0])[i] = 0;

    // ---- weights ----
    short8 wh[4][2]; short8 wx[4]; f32x4 biasv[4];
    short8 wcd[2] = {}; f32x4 bcdv = {0, 0, 0, 0};
    if (gatew) {
#pragma unroll
        for (int g = 0; g < 4; ++g) {
            const float sc = (g == 3) ? 2.f * LOG2E : -LOG2E;
#pragma unroll
            for (int j = 0; j < 4; ++j)
                biasv[g][j] = bl[g * 64 + uw * 16 + grp * 4 + j] * sc;
            const int R = g * 64 + uw * 16 + col;
#pragma unroll
            for (int kt = 0; kt < 2; ++kt)
#pragma unroll
                for (int i = 0; i < 8; ++i)
                    wh[g][kt][i] = (short)f2bf(Wl[R * 80 + 16 + kt * 32 + grp * 8 + i] * sc);
#pragma unroll
            for (int i = 0; i < 8; ++i)
                wx[g][i] = (grp < 2) ? (short)f2bf(Wl[R * 80 + grp * 8 + i] * sc) : (short)0;
        }
    } else {
        // head (unswapped): class lanes fold +log2e; dec lane folds -log2e.
#pragma unroll
        for (int kt = 0; kt < 2; ++kt)
#pragma unroll
            for (int i = 0; i < 8; ++i) {
                const int k = kt * 32 + grp * 8 + i;
                float v = 0.f;
                if (col < 10)       v = Wc[col * 64 + k] * LOG2E;
                else if (col == 10) v = Wd[k] * -LOG2E;
                wcd[kt][i] = (short)f2bf(v);
            }
        const float bv = (col < 10) ? bc[col] * LOG2E
                       : ((col == 10) ? bd[0] * -LOG2E : 0.f);
        bcdv = (f32x4){bv, bv, bv, bv};
    }

    // ---- gate x pipeline: xz[g] = Wx x_t + bias, computed one step ahead ----
    const float* xrow = x + ((size_t)(b0 + col) * Tn) * CIN + grp * 8;  // valid grp<2
    float4 xfA = {0, 0, 0, 0}, xfB = {0, 0, 0, 0};    // floats of x_{t+1}
    f32x4 xz[4] = {};
    const float* xp = xrow + 2 * CIN;                 // x_{t+2} onward
    if (gatew) {
        short8 x0 = {0, 0, 0, 0, 0, 0, 0, 0};
        if (grp < 2) {
            const float4 a = *(const float4*)(xrow);
            const float4 b = *(const float4*)(xrow + 4);
            x0 = pack_bf8(a, b);
            xfA = *(const float4*)(xrow + CIN);
            xfB = *(const float4*)(xrow + CIN + 4);
        }
#pragma unroll
        for (int g = 0; g < 4; ++g)
            xz[g] = __builtin_amdgcn_mfma_f32_16x16x32_bf16(wx[g], x0, biasv[g], 0, 0, 0);
        __builtin_amdgcn_s_setprio(1);   // gate waves are the critical role
    }

    __syncthreads();   // comb[0] zero-fill visible

    float cst[4] = {0, 0, 0, 0};  // gates: c[unit=uw*16+grp*4+j][batch=col]
    float pnd = 1.f;              // head, lanes col==10, row grp*4+uw

    const int row = grp * 4 + uw;        // head-output row this head thread owns
    float* lp_p = out + ((size_t)(b0 + row) * Tn) * NCLS + col;              // [B][T][10]
    float* pt_p = out + (size_t)Bsz * Tn * NCLS + (size_t)(b0 + row) * Tn;   // [B][T]

    for (int t = 0; t < Tn; ++t) {
        const ushort (*rdb)[SH] = comb[t & 1];
        ushort (*wrb)[SH] = comb[(t + 1) & 1];
        if (gatew) {
            // critical path: 2 b128 reads -> 2-chained MFMA (C = xz) -> act -> write
            const short8 hb0 = *(const short8*)&rdb[col][grp * 8];
            const short8 hb1 = *(const short8*)&rdb[col][32 + grp * 8];
            f32x4 acc[4];
#pragma unroll
            for (int g = 0; g < 4; ++g) {
                f32x4 z = __builtin_amdgcn_mfma_f32_16x16x32_bf16(wh[g][0], hb0, xz[g], 0, 0, 0);
                acc[g] = __builtin_amdgcn_mfma_f32_16x16x32_bf16(wh[g][1], hb1, z, 0, 0, 0);
            }
            // off-CP: xz for t+1 from x_{t+1} regs; then issue x_{t+2} loads
            const short8 xn = pack_bf8(xfA, xfB);   // grp>=2 lanes garbage, wx=0 kills
            float4 nA = {0, 0, 0, 0}, nB = {0, 0, 0, 0};
            if (t + 2 < Tn && grp < 2) {
                nA = *(const float4*)(xp);
                nB = *(const float4*)(xp + 4);
            }
            xp += CIN;
#pragma unroll
            for (int g = 0; g < 4; ++g)
                xz[g] = __builtin_amdgcn_mfma_f32_16x16x32_bf16(wx[g], xn, biasv[g], 0, 0, 0);
            xfA = nA; xfB = nB;
            // activations: 4 exp2 + 2 rcp per cell; tanh(c) via Pade(7,6),
            // its division folded into the h-rcp.
            float h[4];
#pragma unroll
            for (int j = 0; j < 4; ++j) {
                const float ei = EXP2F(acc[0][j]);
                const float ef = EXP2F(acc[1][j]);
                const float eo = EXP2F(acc[2][j]);
                const float eg = EXP2F(acc[3][j]);
                const float A  = 1.f + ei, Bv = 1.f + ef;
                const float G1 = eg + 1.f, G2 = eg - 1.f, O = 1.f + eo;
                const float t0  = A * G1;
                const float num = cst[j] * t0 + G2 * Bv;
                const float den = Bv * t0;
                const float cn  = num * RCPF(den);
                cst[j] = cn;
                const float z2 = cn * cn;
                const float t1 = z2 + 378.f;
                const float t2 = __builtin_fmaf(z2, t1, 17325.f);
                const float t3 = __builtin_fmaf(z2, t2, 135135.f);
                const float u1 = __builtin_fmaf(z2, 28.f, 3150.f);
                const float u2 = __builtin_fmaf(z2, u1, 62370.f);
                const float u3 = __builtin_fmaf(z2, u2, 135135.f);
                h[j] = (cn * t3) * RCPF(u3 * O);    // tanh(c) * sigmoid(o)
            }
            const unsigned d0 = cvt_pk_bf16(h[0], h[1]);
            const unsigned d1 = cvt_pk_bf16(h[2], h[3]);
            *(uint2*)&wrb[col][uw * 16 + grp * 4] = (uint2){d0, d1};
        } else {
            // head logits on h_{t-1} (rdb), softmax/store for step t-1
            const short8 ha0 = *(const short8*)&rdb[col][grp * 8];
            const short8 ha1 = *(const short8*)&rdb[col][32 + grp * 8];
            f32x4 cz = bcdv;
            cz = __builtin_amdgcn_mfma_f32_16x16x32_bf16(ha0, wcd[0], cz, 0, 0, 0);
            cz = __builtin_amdgcn_mfma_f32_16x16x32_bf16(ha1, wcd[1], cz, 0, 0, 0);
            if (t > 0) {
                // v pre-scaled: col<10 = logit*log2e ; col==10 = -dec_logit*log2e
                float v = (uw & 1) ? ((uw & 2) ? cz[3] : cz[1])
                                   : ((uw & 2) ? cz[2] : cz[0]);
                const float e = EXP2F(v);              // one exp2 serves both paths
                float s = (col < 10) ? e : 0.f;
                s += __int_as_float(__builtin_amdgcn_ds_swizzle(__float_as_int(s), 0x041F));
                s += __int_as_float(__builtin_amdgcn_ds_swizzle(__float_as_int(s), 0x081F));
                s += __int_as_float(__builtin_amdgcn_ds_swizzle(__float_as_int(s), 0x101F));
                s += __int_as_float(__builtin_amdgcn_ds_swizzle(__float_as_int(s), 0x201F));
                const float lse = __logf(s);
                if (col < 10) {
                    lp_p[0] = v * LN2 - lse;           // natural log-softmax
                } else if (col == 10) {
                    const float d = RCPF(1.f + e);     // sigmoid(dec)
                    pt_p[0] = d * pnd;
                    pnd *= (1.f - d);
                }
                lp_p += NCLS;
                pt_p += 1;
            }
        }
        BARRIER_LDS();
    }

    // epilogue: output step Tn-1 from h_{Tn-1} in comb[Tn&1] (head waves)
    if (!gatew) {
        const ushort (*rdb)[SH] = comb[Tn & 1];
        const short8 ha0 = *(const short8*)&rdb[col][grp * 8];
        const short8 ha1 = *(const short8*)&rdb[col][32 + grp * 8];
        f32x4 cz = bcdv;
        cz = __builtin_amdgcn_mfma_f32_16x16x32_bf16(ha0, wcd[0], cz, 0, 0, 0);
        cz = __builtin_amdgcn_mfma_f32_16x16x32_bf16(ha1, wcd[1], cz, 0, 0, 0);
        float v = (uw & 1) ? ((uw & 2) ? cz[3] : cz[1])
                           : ((uw & 2) ? cz[2] : cz[0]);
        const float e = EXP2F(v);
        float s = (col < 10) ? e : 0.f;
        s += __int_as_float(__builtin_amdgcn_ds_swizzle(__float_as_int(s), 0x041F));
        s += __int_as_float(__builtin_amdgcn_ds_swizzle(__float_as_int(s), 0x081F));
        s += __int_as_float(__builtin_amdgcn_ds_swizzle(__float_as_int(s), 0x101F));
        s += __int_as_float(__builtin_amdgcn_ds_swizzle(__float_as_int(s), 0x201F));
        const float lse = __logf(s);
        if (col < 10)       lp_p[0] = v * LN2 - lse;
        else if (col == 10) pt_p[0] = pnd;   // is_last: Pt = pnd_{T-1}
    }
}

extern "C" void kernel_launch(void* const* d_in, const int* in_sizes, int n_in,
                              void* d_out, int out_size, void* d_ws, size_t ws_size,
                              hipStream_t stream) {
    const float* x  = (const float*)d_in[0];
    const float* Wl = (const float*)d_in[1];
    const float* bl = (const float*)d_in[2];
    const float* Wc = (const float*)d_in[3];
    const float* bc = (const float*)d_in[4];
    const float* Wd = (const float*)d_in[5];
    const float* bd = (const float*)d_in[6];
    float* out = (float*)d_out;

    hipLaunchKernelGGL(dualrnn_fused, dim3(Bsz / MB), dim3(512), 0, stream,
                       x, Wl, bl, Wc, bc, Wd, bd, out);
}